// Round 8
// baseline (720.353 us; speedup 1.0000x reference)
//
#include <hip/hip_runtime.h>

#define NWIN 4096
#define KTOK 32
#define CH 256
#define NH 8
#define NTOK (NWIN*KTOK)

typedef unsigned short bf16u;
typedef __attribute__((ext_vector_type(4))) float f32x4;
typedef __attribute__((ext_vector_type(4))) unsigned short u16x4;
typedef __attribute__((ext_vector_type(8))) unsigned short u16x8;
typedef __attribute__((ext_vector_type(8))) __bf16 bf16x8;

__device__ __forceinline__ unsigned short f2bf(float f) {
  unsigned u = __builtin_bit_cast(unsigned, f);
  u += 0x7fffu + ((u >> 16) & 1u);
  return (unsigned short)(u >> 16);
}

__device__ __forceinline__ f32x4 mfma16(bf16x8 a, bf16x8 b, f32x4 c) {
  return __builtin_amdgcn_mfma_f32_16x16x32_bf16(a, b, c, 0, 0, 0);
}

__device__ __forceinline__ void gl16(const void* g, void* l) {
  __builtin_amdgcn_global_load_lds(
      (const __attribute__((address_space(1))) unsigned int*)g,
      (__attribute__((address_space(3))) unsigned int*)l, 16, 0, 0);
}

__device__ __forceinline__ float gelu_f(float x) {
  float u = x + 0.044715f * x * x * x;
  return x * __builtin_amdgcn_rcpf(1.f + __expf(-1.5957691216057308f * u));
}

// ---- weight prep: W (K x N) f32 -> Wt (N x K) bf16 ----
__global__ __launch_bounds__(256) void wprep_kernel(const float* __restrict__ W,
                                                    bf16u* __restrict__ Wt,
                                                    int Kd, int Nd) {
  int idx = blockIdx.x * 256 + threadIdx.x;
  if (idx >= Kd * Nd) return;
  int k = idx / Nd, n = idx - k * Nd;
  Wt[n * Kd + k] = f2bf(W[idx]);
}

// ---- LayerNorm: one wave per 256-col row, f32 in -> bf16 out ----
__global__ __launch_bounds__(256) void ln_kernel(const float* __restrict__ x,
                                                 const float* __restrict__ g,
                                                 const float* __restrict__ b,
                                                 bf16u* __restrict__ y) {
  const int row = blockIdx.x * 4 + (threadIdx.x >> 6);
  const int lane = threadIdx.x & 63;
  const size_t base = (size_t)row * CH + lane * 4;
  const f32x4 v = *(const f32x4*)(x + base);
  float s = v[0] + v[1] + v[2] + v[3];
  float q = v[0]*v[0] + v[1]*v[1] + v[2]*v[2] + v[3]*v[3];
  #pragma unroll
  for (int d = 32; d; d >>= 1) { s += __shfl_xor(s, d); q += __shfl_xor(q, d); }
  const float mean = s * (1.f/256.f);
  const float rs = rsqrtf(q * (1.f/256.f) - mean*mean + 1e-5f);
  const f32x4 gv = *(const f32x4*)(g + lane*4);
  const f32x4 bv = *(const f32x4*)(b + lane*4);
  u16x4 o;
  #pragma unroll
  for (int d = 0; d < 4; ++d) o[d] = f2bf((v[d]-mean)*rs*gv[d] + bv[d]);
  *(u16x4*)(y + base) = o;
}

// ---- weight-stationary GEMM for K=256: B [64n][256k] in LDS (swizzled),
// A in registers (4 m-chunks/wave), barrier-free K-loop, 16 MFMA : 4 ds_read.
// EPI 0: +bias -> bf16 ; EPI 1: +bias,gelu -> bf16
template<int EPI>
__global__ __launch_bounds__(256, 2)
void gemmW_kernel(const bf16u* __restrict__ A, const bf16u* __restrict__ Bt,
                  const float* __restrict__ bias, bf16u* __restrict__ out,
                  int N, int nx) {
  __shared__ __align__(16) char lds[32768];
  const int tid = threadIdx.x, lane = tid & 63, wv = tid >> 6;
  const int lo = lane & 15, hi = lane >> 4;
  const int nwg = gridDim.x, cpx = nwg >> 3;
  const int swz = (blockIdx.x & 7) * cpx + (blockIdx.x >> 3);
  const int by = swz / nx, bx = swz - by * nx;
  const int bm = by * 256, bn = bx * 64;

  // A-frags: rows bm + wv*64 + mc*16 + lo, k = j*32 + hi*8 (A-frag layout)
  bf16x8 a[4][8];
  {
    const bf16u* ap = A + (size_t)(bm + wv*64 + lo) * 256 + hi*8;
    #pragma unroll
    for (int mc = 0; mc < 4; ++mc)
      #pragma unroll
      for (int j = 0; j < 8; ++j)
        a[mc][j] = *(const bf16x8*)(ap + (size_t)mc*16*256 + j*32);
  }
  // bias preload (per-lane, 4 cols)
  float bv[4];
  #pragma unroll
  for (int nf = 0; nf < 4; ++nf) bv[nf] = bias[bn + nf*16 + lo];

  // stage B panel once, pre-swizzled source so linear gl16 dest = swizzled LDS
  #pragma unroll
  for (int t = 0; t < 8; ++t) {
    const int c = t*256 + tid;           // 16B-granule id, 0..2047
    const int row = c >> 5, g = c & 31;
    gl16((const char*)Bt + (size_t)(bn + row) * 512 + ((g ^ (row & 7)) * 16),
         lds + c*16);
  }
  __syncthreads();   // drains gl16 + A-loads

  f32x4 acc[4][4] = {};
  #pragma unroll
  for (int j = 0; j < 8; ++j) {
    bf16x8 b[4];
    #pragma unroll
    for (int nf = 0; nf < 4; ++nf) {
      const int row = nf*16 + lo;
      const int g = (j*4 + hi) ^ (row & 7);
      b[nf] = *(const bf16x8*)(lds + row*512 + g*16);
    }
    #pragma unroll
    for (int mc = 0; mc < 4; ++mc)
      #pragma unroll
      for (int nf = 0; nf < 4; ++nf)
        acc[mc][nf] = mfma16(a[mc][j], b[nf], acc[mc][nf]);
  }

  // direct epilogue: m = bm + wv*64 + mc*16 + hi*4 + r, n = bn + nf*16 + lo
  #pragma unroll
  for (int mc = 0; mc < 4; ++mc)
    #pragma unroll
    for (int nf = 0; nf < 4; ++nf) {
      const int n = bn + nf*16 + lo;
      #pragma unroll
      for (int r = 0; r < 4; ++r) {
        const int m = bm + wv*64 + mc*16 + hi*4 + r;
        float v = acc[mc][nf][r] + bv[nf];
        if constexpr (EPI == 1) v = gelu_f(v);
        out[(size_t)m*N + n] = f2bf(v);
      }
    }
}

// ---- 128x128 MFMA GEMM, 2-buffer pipeline (r5-proven) — for K=1024 ----
template<int EPI>
__global__ __launch_bounds__(256, 4)
void gemm_kernel(const bf16u* __restrict__ A, const bf16u* __restrict__ Bt,
                 const float* __restrict__ bias, const float* __restrict__ resid,
                 void* __restrict__ out, int M, int N, int K, int nx) {
  __shared__ __align__(16) char lds[32768];   // 2 x (As 8K | Bs 8K)
  const int tid = threadIdx.x;
  const int lane = tid & 63;
  const int wv = tid >> 6;
  const int lo = lane & 15, hi = lane >> 4;
  const int nwg = gridDim.x;
  const int cpx = nwg >> 3;
  const int swz = (blockIdx.x & 7) * cpx + (blockIdx.x >> 3);
  const int by = swz / nx, bx = swz - by * nx;
  const int bm = by * 128, bn = bx * 128;
  const int wm = (wv >> 1) * 64, wn = (wv & 1) * 64;

  f32x4 acc[4][4] = {};

  const int srow = tid >> 2;
  const int sk = (tid & 3) * 16;
  const size_t rstep = (size_t)64 * K * 2;
  const char* gA = (const char*)(A + (size_t)(bm + srow) * K) + sk;
  const char* gB = (const char*)(Bt + (size_t)(bn + srow) * K) + sk;

  auto STAGE = [&](int b, int k0) {
    char* As = lds + b * 16384;
    char* Bs = As + 8192;
    const char* ga = gA + k0 * 2;
    const char* gb = gB + k0 * 2;
    gl16(ga,         As + tid*16);
    gl16(ga + rstep, As + 4096 + tid*16);
    gl16(gb,         Bs + tid*16);
    gl16(gb + rstep, Bs + 4096 + tid*16);
  };

  STAGE(0, 0);
  int cur = 0;
  for (int k0 = 0; ; k0 += 32) {
    const bool has_next = (k0 + 32 < K);
    if (has_next) {
      STAGE(cur ^ 1, k0 + 32);
      asm volatile("s_waitcnt vmcnt(4)" ::: "memory");
    } else {
      asm volatile("s_waitcnt vmcnt(0)" ::: "memory");
    }
    __builtin_amdgcn_sched_barrier(0);
    __builtin_amdgcn_s_barrier();
    const char* As = lds + cur * 16384;
    const char* Bs = As + 8192;
    bf16x8 af[4], bfv[4];
    #pragma unroll
    for (int i = 0; i < 4; ++i) {
      af[i]  = *(const bf16x8*)(As + (wm + i*16 + lo)*64 + hi*16);
      bfv[i] = *(const bf16x8*)(Bs + (wn + i*16 + lo)*64 + hi*16);
    }
    #pragma unroll
    for (int i = 0; i < 4; ++i)
      #pragma unroll
      for (int j = 0; j < 4; ++j)
        acc[i][j] = mfma16(af[i], bfv[j], acc[i][j]);
    if (!has_next) break;
    __builtin_amdgcn_s_barrier();
    cur ^= 1;
  }

  __syncthreads();
  float* Ls = (float*)(lds + wv * 4352);   // [16][68] per wave
  const int mb = bm + wm, nb = bn + wn;
  const int lrow = lane >> 3;
  const int lcol = (lane & 7) * 8;
  const f32x4 bv0 = *(const f32x4*)(bias + nb + lcol);
  const f32x4 bv1 = *(const f32x4*)(bias + nb + lcol + 4);

  #pragma unroll
  for (int i = 0; i < 4; ++i) {
    #pragma unroll
    for (int j = 0; j < 4; ++j)
      #pragma unroll
      for (int r = 0; r < 4; ++r)
        Ls[(hi*4 + r)*68 + j*16 + lo] = acc[i][j][r];
    #pragma unroll
    for (int p = 0; p < 2; ++p) {
      const int rr = p*8 + lrow;
      const int m = mb + i*16 + rr;
      f32x4 v0 = *(const f32x4*)(Ls + rr*68 + lcol);
      f32x4 v1 = *(const f32x4*)(Ls + rr*68 + lcol + 4);
      v0 += bv0; v1 += bv1;
      if constexpr (EPI == 2) {
        const float* rp = resid + (size_t)m*N + nb + lcol;
        v0 += *(const f32x4*)rp;
        v1 += *(const f32x4*)(rp + 4);
        float* op = (float*)out + (size_t)m*N + nb + lcol;
        *(f32x4*)op = v0;
        *(f32x4*)(op + 4) = v1;
      } else {
        if constexpr (EPI == 1) {
          #pragma unroll
          for (int d = 0; d < 4; ++d) { v0[d] = gelu_f(v0[d]); v1[d] = gelu_f(v1[d]); }
        }
        u16x8 o8;
        #pragma unroll
        for (int d = 0; d < 4; ++d) { o8[d] = f2bf(v0[d]); o8[4+d] = f2bf(v1[d]); }
        *(u16x8*)((bf16u*)out + (size_t)m*N + nb + lcol) = o8;
      }
    }
  }
}

// ---- proj GEMM, 128x256 full-N tile, fused residual + LN2 ----
__global__ __launch_bounds__(256, 2)
void gemmP_kernel(const bf16u* __restrict__ A, const bf16u* __restrict__ Bt,
                  const float* __restrict__ bias, const float* __restrict__ resid,
                  float* __restrict__ out, bf16u* __restrict__ xln,
                  const float* __restrict__ g2, const float* __restrict__ b2) {
  __shared__ __align__(16) char lds[73728];   // 3 x (As 8K | Bs 16K); epi 2x33KB
  const int tid = threadIdx.x, lane = tid & 63, wv = tid >> 6;
  const int lo = lane & 15, hi = lane >> 4;
  const int nwg = gridDim.x, cpx = nwg >> 3;
  const int by = (blockIdx.x & 7) * cpx + (blockIdx.x >> 3);
  const int bm = by * 128;
  const int wmh = wv >> 1;
  const int wm = wmh * 64, wn = (wv & 1) * 128;

  f32x4 acc[4][8] = {};

  const int arow = tid >> 2;
  const int sk = (tid & 3) * 16;
  const char* gA = (const char*)(A + (size_t)(bm + arow) * 256) + sk;
  const char* gB = (const char*)(Bt + (size_t)arow * 256) + sk;

  auto STAGE = [&](int b, int kt) {
    char* As = lds + b * 24576;
    char* Bs = As + 8192;
    const char* ga = gA + kt * 64;
    const char* gb = gB + kt * 64;
    gl16(ga,         As + arow*64 + sk);
    gl16(ga + 32768, As + 4096 + arow*64 + sk);
    #pragma unroll
    for (int p = 0; p < 4; ++p)
      gl16(gb + p*32768, Bs + p*4096 + arow*64 + sk);
  };

  STAGE(0, 0);
  STAGE(1, 1);
  int cur = 0;
  for (int t = 0; t < 8; ++t) {
    if (t + 2 < 8) {
      STAGE((cur + 2) % 3, t + 2);
      asm volatile("s_waitcnt vmcnt(12)" ::: "memory");
    } else if (t + 1 < 8) {
      asm volatile("s_waitcnt vmcnt(6)" ::: "memory");
    } else {
      asm volatile("s_waitcnt vmcnt(0)" ::: "memory");
    }
    __builtin_amdgcn_sched_barrier(0);
    __builtin_amdgcn_s_barrier();
    const char* As = lds + cur * 24576;
    const char* Bs = As + 8192;
    bf16x8 af[4], bf8[8];
    #pragma unroll
    for (int i = 0; i < 4; ++i)
      af[i] = *(const bf16x8*)(As + (wm + i*16 + lo)*64 + hi*16);
    #pragma unroll
    for (int j = 0; j < 8; ++j)
      bf8[j] = *(const bf16x8*)(Bs + (wn + j*16 + lo)*64 + hi*16);
    #pragma unroll
    for (int i = 0; i < 4; ++i)
      #pragma unroll
      for (int j = 0; j < 8; ++j)
        acc[i][j] = mfma16(af[i], bf8[j], acc[i][j]);
    __builtin_amdgcn_s_barrier();
    cur = (cur + 1) % 3;
  }

  __syncthreads();
  float* LsE = (float*)lds;            // [2][32][260] f32
  const int c4 = (tid & 3) * 4;
  const int row64 = tid >> 2;
  const int reg = row64 >> 5, rloc = row64 & 31;
  #pragma unroll
  for (int rr = 0; rr < 2; ++rr) {
    #pragma unroll
    for (int i2 = 0; i2 < 2; ++i2) {
      const int i = rr*2 + i2;
      #pragma unroll
      for (int j = 0; j < 8; ++j)
        #pragma unroll
        for (int r = 0; r < 4; ++r)
          LsE[wmh*8320 + (i2*16 + hi*4 + r)*260 + wn + j*16 + lo] = acc[i][j][r];
    }
    __syncthreads();
    const int grow = bm + reg*64 + rr*32 + rloc;
    f32x4 d2[16];
    float sum = 0.f, sq = 0.f;
    #pragma unroll
    for (int k = 0; k < 16; ++k) {
      const int col = c4 + k*16;
      f32x4 v = *(const f32x4*)&LsE[reg*8320 + rloc*260 + col];
      v += *(const f32x4*)(bias + col);
      v += *(const f32x4*)(resid + (size_t)grow*256 + col);
      d2[k] = v;
      sum += v[0] + v[1] + v[2] + v[3];
      sq  += v[0]*v[0] + v[1]*v[1] + v[2]*v[2] + v[3]*v[3];
      *(f32x4*)(out + (size_t)grow*256 + col) = v;
    }
    sum += __shfl_xor(sum, 1); sq += __shfl_xor(sq, 1);
    sum += __shfl_xor(sum, 2); sq += __shfl_xor(sq, 2);
    const float mean = sum * (1.f/256.f);
    const float rs = rsqrtf(sq * (1.f/256.f) - mean*mean + 1e-5f);
    #pragma unroll
    for (int k = 0; k < 16; ++k) {
      const int col = c4 + k*16;
      const f32x4 gv = *(const f32x4*)(g2 + col);
      const f32x4 bvv = *(const f32x4*)(b2 + col);
      u16x4 o;
      #pragma unroll
      for (int d = 0; d < 4; ++d)
        o[d] = f2bf((d2[k][d] - mean) * rs * gv[d] + bvv[d]);
      *(u16x4*)(xln + (size_t)grow*256 + col) = o;
    }
    __syncthreads();
  }
}

// ---- fused window attention: one block per window, 2 heads per wave ----
__global__ __launch_bounds__(256, 2)
void attn_kernel(const bf16u* __restrict__ qkv, const float* __restrict__ mask,
                 const int* __restrict__ relp, const float* __restrict__ rpe,
                 bf16u* __restrict__ outp) {
  const int w = blockIdx.x;
  const int tid = threadIdx.x, lane = tid & 63, wv = tid >> 6;
  const int lo = lane & 15, hi = lane >> 4;

  __shared__ __align__(16) bf16u sQK[32*520];
  __shared__ __align__(16) bf16u sV[32][264];
  __shared__ __align__(16) bf16u sP[4][32][44];
  __shared__ float sTabT[8][156];
  __shared__ int sRel[1024];
  __shared__ float sMask[32][33];

  const size_t qbase = (size_t)w * (32*768);
  {
    #pragma unroll
    for (int t = 0; t < 8; ++t) {
      int i = tid + t*256;
      int tok = i >> 6;
      int cb = (i & 63) * 16;
      *(u16x8*)((char*)sQK + tok*1040 + cb) =
          *(const u16x8*)((const char*)(qkv + qbase) + tok*1536 + cb);
    }
    #pragma unroll
    for (int t = 0; t < 4; ++t) {
      int i = tid + t*256;
      int tok = i >> 5, c8 = i & 31;
      *(u16x8*)&sV[tok][c8*8] = *(const u16x8*)(qkv + qbase + tok*768 + 512 + c8*8);
    }
    for (int i = tid; i < 1224; i += 256)
      sTabT[i & 7][i >> 3] = rpe[i];
    #pragma unroll
    for (int t = 0; t < 4; ++t) {
      int i = tid + t*256;
      const int* rp = relp + ((size_t)w*1024 + i)*3;
      int r0 = rp[0], r1 = rp[1], r2 = rp[2];
      r0 = min(max(r0, -25), 25) + 25;
      r1 = min(max(r1, -25), 25) + 76;
      r2 = min(max(r2, -25), 25) + 127;
      sRel[i] = r0 | (r1 << 8) | (r2 << 16);
    }
    #pragma unroll
    for (int d = 0; d < 4; ++d) {
      int i = tid*4 + d;
      sMask[i >> 5][i & 31] = mask[(size_t)w*1024 + i];
    }
  }
  __syncthreads();

  const float scale = 0.17677669529663687f;
  #pragma unroll
  for (int e = 0; e < 2; ++e) {
    const int h = wv*2 + e;
    bf16x8 qf[2], kf[2];
    #pragma unroll
    for (int rf = 0; rf < 2; ++rf) {
      int tok = rf*16 + lo;
      qf[rf] = *(const bf16x8*)((const char*)sQK + tok*1040 + h*64 + hi*16);
      kf[rf] = *(const bf16x8*)((const char*)sQK + tok*1040 + 512 + h*64 + hi*16);
    }
    f32x4 S[2][2] = {};
    #pragma unroll
    for (int rf = 0; rf < 2; ++rf)
      #pragma unroll
      for (int cf = 0; cf < 2; ++cf)
        S[rf][cf] = mfma16(qf[rf], kf[cf], S[rf][cf]);
    #pragma unroll
    for (int rf = 0; rf < 2; ++rf)
      #pragma unroll
      for (int cf = 0; cf < 2; ++cf)
        #pragma unroll
        for (int r = 0; r < 4; ++r) {
          const int qq = rf*16 + hi*4 + r;
          const int kk = cf*16 + lo;
          const int pk = sRel[qq*32 + kk];
          const float bsum = sTabT[h][pk & 255] + sTabT[h][(pk >> 8) & 255]
                           + sTabT[h][(pk >> 16) & 255];
          S[rf][cf][r] = S[rf][cf][r] * scale + bsum + sMask[qq][kk];
        }
    #pragma unroll
    for (int rf = 0; rf < 2; ++rf)
      #pragma unroll
      for (int r = 0; r < 4; ++r) {
        float m0 = fmaxf(S[rf][0][r], S[rf][1][r]);
        #pragma unroll
        for (int d = 1; d < 16; d <<= 1) m0 = fmaxf(m0, __shfl_xor(m0, d));
        const float p0 = __expf(S[rf][0][r] - m0);
        const float p1 = __expf(S[rf][1][r] - m0);
        float ss = p0 + p1;
        #pragma unroll
        for (int d = 1; d < 16; d <<= 1) ss += __shfl_xor(ss, d);
        const float inv = 1.f / ss;
        S[rf][0][r] = p0 * inv;
        S[rf][1][r] = p1 * inv;
      }
    #pragma unroll
    for (int rf = 0; rf < 2; ++rf)
      #pragma unroll
      for (int cf = 0; cf < 2; ++cf)
        #pragma unroll
        for (int r = 0; r < 4; ++r)
          sP[wv][rf*16 + hi*4 + r][cf*16 + lo] = f2bf(S[rf][cf][r]);
    f32x4 O[2][2] = {};
    #pragma unroll
    for (int rf = 0; rf < 2; ++rf) {
      bf16x8 pf;
      *(u16x4*)&pf       = *(const u16x4*)&sP[wv][rf*16 + lo][hi*8];
      *((u16x4*)&pf + 1) = *(const u16x4*)&sP[wv][rf*16 + lo][hi*8 + 4];
      #pragma unroll
      for (int cf = 0; cf < 2; ++cf) {
        bf16x8 vf;
        #pragma unroll
        for (int j = 0; j < 8; ++j)
          ((bf16u*)&vf)[j] = sV[hi*8 + j][h*32 + cf*16 + lo];
        O[rf][cf] = mfma16(pf, vf, O[rf][cf]);
      }
    }
    #pragma unroll
    for (int rf = 0; rf < 2; ++rf)
      #pragma unroll
      for (int cf = 0; cf < 2; ++cf)
        #pragma unroll
        for (int r = 0; r < 4; ++r) {
          const int qq = rf*16 + hi*4 + r;
          outp[(size_t)(w*32 + qq)*256 + h*32 + cf*16 + lo] = f2bf(O[rf][cf][r]);
        }
  }
}

extern "C" void kernel_launch(void* const* d_in, const int* in_sizes, int n_in,
                              void* d_out, int out_size, void* d_ws, size_t ws_size,
                              hipStream_t stream) {
  const float* data   = (const float*)d_in[0];
  const float* mask   = (const float*)d_in[1];
  const int*   relp   = (const int*)d_in[2];
  const float* qkv_w  = (const float*)d_in[3];
  const float* qkv_b  = (const float*)d_in[4];
  const float* proj_w = (const float*)d_in[5];
  const float* proj_b = (const float*)d_in[6];
  const float* rpe    = (const float*)d_in[7];
  const float* ln1_g  = (const float*)d_in[8];
  const float* ln1_b  = (const float*)d_in[9];
  const float* ln2_g  = (const float*)d_in[10];
  const float* ln2_b  = (const float*)d_in[11];
  const float* fc1_w  = (const float*)d_in[12];
  const float* fc1_b  = (const float*)d_in[13];
  const float* fc2_w  = (const float*)d_in[14];
  const float* fc2_b  = (const float*)d_in[15];

  char* ws = (char*)d_ws;
  bf16u* wt_qkv  = (bf16u*)(ws);                 // 768x256
  bf16u* wt_proj = (bf16u*)(ws + 393216);        // 256x256
  bf16u* wt_fc1  = (bf16u*)(ws + 524288);        // 1024x256
  bf16u* wt_fc2  = (bf16u*)(ws + 1048576);       // 256x1024
  char*  big     = ws + 2097152;
  bf16u* xbuf    = (bf16u*)big;                        // attn out (67MB)
  bf16u* qkvbuf  = (bf16u*)(big + 67108864);           // qkv (201MB)
  bf16u* h1      = (bf16u*)big;                        // fc1 out (overlays dead bufs)
  bf16u* xnorm   = (bf16u*)(big + 268435456);          // ln1-out / fused-ln2-out
  float* data2   = (float*)d_out;                // residual stream lives in d_out

  wprep_kernel<<<768, 256, 0, stream>>>(qkv_w, wt_qkv, 256, 768);
  wprep_kernel<<<256, 256, 0, stream>>>(proj_w, wt_proj, 256, 256);
  wprep_kernel<<<1024, 256, 0, stream>>>(fc1_w, wt_fc1, 256, 1024);
  wprep_kernel<<<1024, 256, 0, stream>>>(fc2_w, wt_fc2, 1024, 256);

  ln_kernel<<<32768, 256, 0, stream>>>(data, ln1_g, ln1_b, xnorm);
  gemmW_kernel<0><<<12*512, 256, 0, stream>>>(xnorm, wt_qkv, qkv_b, qkvbuf, 768, 12);
  attn_kernel<<<NWIN, 256, 0, stream>>>(qkvbuf, mask, relp, rpe, xbuf);
  gemmP_kernel<<<1024, 256, 0, stream>>>(xbuf, wt_proj, proj_b, data,
                                         data2, xnorm, ln2_g, ln2_b);
  gemmW_kernel<1><<<16*512, 256, 0, stream>>>(xnorm, wt_fc1, fc1_b, h1, 1024, 16);
  gemm_kernel<2><<<2*1024, 256, 0, stream>>>(h1, wt_fc2, fc2_b, data2,
                                             d_out, NTOK, 256, 1024, 2);
}

// Round 9
// 626.451 us; speedup vs baseline: 1.1499x; 1.1499x over previous
//
#include <hip/hip_runtime.h>

#define NWIN 4096
#define KTOK 32
#define CH 256
#define NH 8
#define NTOK (NWIN*KTOK)

typedef unsigned short bf16u;
typedef __attribute__((ext_vector_type(4))) float f32x4;
typedef __attribute__((ext_vector_type(4))) unsigned short u16x4;
typedef __attribute__((ext_vector_type(8))) unsigned short u16x8;
typedef __attribute__((ext_vector_type(8))) __bf16 bf16x8;

__device__ __forceinline__ unsigned short f2bf(float f) {
  unsigned u = __builtin_bit_cast(unsigned, f);
  u += 0x7fffu + ((u >> 16) & 1u);
  return (unsigned short)(u >> 16);
}

__device__ __forceinline__ f32x4 mfma16(bf16x8 a, bf16x8 b, f32x4 c) {
  return __builtin_amdgcn_mfma_f32_16x16x32_bf16(a, b, c, 0, 0, 0);
}

__device__ __forceinline__ void gl16(const void* g, void* l) {
  __builtin_amdgcn_global_load_lds(
      (const __attribute__((address_space(1))) unsigned int*)g,
      (__attribute__((address_space(3))) unsigned int*)l, 16, 0, 0);
}

__device__ __forceinline__ float gelu_f(float x) {
  float u = x + 0.044715f * x * x * x;
  return x * __builtin_amdgcn_rcpf(1.f + __expf(-1.5957691216057308f * u));
}

// ---- weight prep: W (K x N) f32 -> Wt (N x K) bf16 ----
__global__ __launch_bounds__(256) void wprep_kernel(const float* __restrict__ W,
                                                    bf16u* __restrict__ Wt,
                                                    int Kd, int Nd) {
  int idx = blockIdx.x * 256 + threadIdx.x;
  if (idx >= Kd * Nd) return;
  int k = idx / Nd, n = idx - k * Nd;
  Wt[n * Kd + k] = f2bf(W[idx]);
}

// ---- LayerNorm: one wave per 256-col row, f32 in -> bf16 out ----
__global__ __launch_bounds__(256) void ln_kernel(const float* __restrict__ x,
                                                 const float* __restrict__ g,
                                                 const float* __restrict__ b,
                                                 bf16u* __restrict__ y) {
  const int row = blockIdx.x * 4 + (threadIdx.x >> 6);
  const int lane = threadIdx.x & 63;
  const size_t base = (size_t)row * CH + lane * 4;
  const f32x4 v = *(const f32x4*)(x + base);
  float s = v[0] + v[1] + v[2] + v[3];
  float q = v[0]*v[0] + v[1]*v[1] + v[2]*v[2] + v[3]*v[3];
  #pragma unroll
  for (int d = 32; d; d >>= 1) { s += __shfl_xor(s, d); q += __shfl_xor(q, d); }
  const float mean = s * (1.f/256.f);
  const float rs = rsqrtf(q * (1.f/256.f) - mean*mean + 1e-5f);
  const f32x4 gv = *(const f32x4*)(g + lane*4);
  const f32x4 bv = *(const f32x4*)(b + lane*4);
  u16x4 o;
  #pragma unroll
  for (int d = 0; d < 4; ++d) o[d] = f2bf((v[d]-mean)*rs*gv[d] + bv[d]);
  *(u16x4*)(y + base) = o;
}

// ---- 256x256 MFMA GEMM: 8 waves (512 thr), 128x64/wave, 3-buffer ring ----
// 32 MFMA : 12 ds_read per wave per K-step -> past the LDS-port ceiling.
// EPI 0: +bias -> bf16 ; EPI 1: +bias,gelu -> bf16 ; EPI 2: +bias+resid -> f32
template<int EPI>
__global__ __launch_bounds__(512, 2)
void gemm256_kernel(const bf16u* __restrict__ A, const bf16u* __restrict__ Bt,
                    const float* __restrict__ bias, const float* __restrict__ resid,
                    void* __restrict__ out, int N, int K, int nx) {
  __shared__ __align__(16) char lds[98304];   // 3 x (As 16K | Bs 16K)
  const int tid = threadIdx.x;
  const int lane = tid & 63;
  const int wv = tid >> 6;                    // 0..7
  const int lo = lane & 15, hi = lane >> 4;
  const int wr = wv >> 2, wc = wv & 3;        // 2M x 4N wave grid
  const int nwg = gridDim.x;
  const int cpx = nwg >> 3;
  const int swz = (blockIdx.x & 7) * cpx + (blockIdx.x >> 3);
  const int by = swz / nx, bx = swz - by * nx;
  const int bm = by * 256, bn = bx * 256;

  f32x4 acc[8][4] = {};

  // staging geometry: granule c in [0,1024) per tile; row=c>>2, g=c&3
  const int srow = tid >> 2;                  // 0..127 (first half)
  const int sg = (tid & 3) * 16;
  const char* pA0 = (const char*)(A + (size_t)(bm + srow) * K) + sg;
  const char* pA1 = (const char*)(A + (size_t)(bm + 128 + srow) * K) + sg;
  const char* pB0 = (const char*)(Bt + (size_t)(bn + srow) * K) + sg;
  const char* pB1 = (const char*)(Bt + (size_t)(bn + 128 + srow) * K) + sg;

  auto STAGE = [&](int b, int kt) {
    char* base = lds + b * 32768;
    const int ko = kt * 64;
    gl16(pA0 + ko, base + tid*16);
    gl16(pA1 + ko, base + 8192 + tid*16);
    gl16(pB0 + ko, base + 16384 + tid*16);
    gl16(pB1 + ko, base + 24576 + tid*16);
  };

  const int nt = K >> 5;
  STAGE(0, 0);
  STAGE(1, 1);
  int cur = 0;
  for (int t = 0; t < nt; ++t) {
    if (t + 2 < nt) {
      STAGE((cur + 2) % 3, t + 2);
      asm volatile("s_waitcnt vmcnt(8)" ::: "memory");
    } else if (t + 1 < nt) {
      asm volatile("s_waitcnt vmcnt(4)" ::: "memory");
    } else {
      asm volatile("s_waitcnt vmcnt(0)" ::: "memory");
    }
    __builtin_amdgcn_sched_barrier(0);
    __builtin_amdgcn_s_barrier();
    const char* As = lds + cur * 32768;
    const char* Bs = As + 16384;
    bf16x8 af[8], bf[4];
    #pragma unroll
    for (int i = 0; i < 8; ++i)
      af[i] = *(const bf16x8*)(As + (wr*128 + i*16 + lo)*64 + hi*16);
    #pragma unroll
    for (int j = 0; j < 4; ++j)
      bf[j] = *(const bf16x8*)(Bs + (wc*64 + j*16 + lo)*64 + hi*16);
    __builtin_amdgcn_s_setprio(1);
    #pragma unroll
    for (int i = 0; i < 8; ++i)
      #pragma unroll
      for (int j = 0; j < 4; ++j)
        acc[i][j] = mfma16(af[i], bf[j], acc[i][j]);
    __builtin_amdgcn_s_setprio(0);
    __builtin_amdgcn_s_barrier();
    cur = (cur + 1) % 3;
  }

  __syncthreads();  // buffers dead; reuse as per-wave epilogue bounce
  float* Ls = (float*)(lds + wv * 4352);      // [16][68] f32 per wave
  const int mb = bm + wr*128, nb = bn + wc*64;
  const int lrow = lane >> 3;                 // 0..7
  const int lcol = (lane & 7) * 8;            // 0..56
  const f32x4 bv0 = *(const f32x4*)(bias + nb + lcol);
  const f32x4 bv1 = *(const f32x4*)(bias + nb + lcol + 4);

  #pragma unroll
  for (int i = 0; i < 8; ++i) {
    #pragma unroll
    for (int j = 0; j < 4; ++j)
      #pragma unroll
      for (int r = 0; r < 4; ++r)
        Ls[(hi*4 + r)*68 + j*16 + lo] = acc[i][j][r];
    #pragma unroll
    for (int p = 0; p < 2; ++p) {
      const int rr = p*8 + lrow;
      const int m = mb + i*16 + rr;
      f32x4 v0 = *(const f32x4*)(Ls + rr*68 + lcol);
      f32x4 v1 = *(const f32x4*)(Ls + rr*68 + lcol + 4);
      v0 += bv0; v1 += bv1;
      if constexpr (EPI == 2) {
        const float* rp = resid + (size_t)m*N + nb + lcol;
        v0 += *(const f32x4*)rp;
        v1 += *(const f32x4*)(rp + 4);
        float* op = (float*)out + (size_t)m*N + nb + lcol;
        *(f32x4*)op = v0;
        *(f32x4*)(op + 4) = v1;
      } else {
        if constexpr (EPI == 1) {
          #pragma unroll
          for (int d = 0; d < 4; ++d) { v0[d] = gelu_f(v0[d]); v1[d] = gelu_f(v1[d]); }
        }
        u16x8 o8;
        #pragma unroll
        for (int d = 0; d < 4; ++d) { o8[d] = f2bf(v0[d]); o8[4+d] = f2bf(v1[d]); }
        *(u16x8*)((bf16u*)out + (size_t)m*N + nb + lcol) = o8;
      }
    }
  }
}

// ---- proj GEMM, 128x256 full-N tile, fused residual + LN2 ----
__global__ __launch_bounds__(256, 2)
void gemmP_kernel(const bf16u* __restrict__ A, const bf16u* __restrict__ Bt,
                  const float* __restrict__ bias, const float* __restrict__ resid,
                  float* __restrict__ out, bf16u* __restrict__ xln,
                  const float* __restrict__ g2, const float* __restrict__ b2) {
  __shared__ __align__(16) char lds[73728];   // 3 x (As 8K | Bs 16K); epi 2x33KB
  const int tid = threadIdx.x, lane = tid & 63, wv = tid >> 6;
  const int lo = lane & 15, hi = lane >> 4;
  const int nwg = gridDim.x, cpx = nwg >> 3;
  const int by = (blockIdx.x & 7) * cpx + (blockIdx.x >> 3);
  const int bm = by * 128;
  const int wmh = wv >> 1;
  const int wm = wmh * 64, wn = (wv & 1) * 128;

  f32x4 acc[4][8] = {};

  const int arow = tid >> 2;
  const int sk = (tid & 3) * 16;
  const char* gA = (const char*)(A + (size_t)(bm + arow) * 256) + sk;
  const char* gB = (const char*)(Bt + (size_t)arow * 256) + sk;

  auto STAGE = [&](int b, int kt) {
    char* As = lds + b * 24576;
    char* Bs = As + 8192;
    const char* ga = gA + kt * 64;
    const char* gb = gB + kt * 64;
    gl16(ga,         As + arow*64 + sk);
    gl16(ga + 32768, As + 4096 + arow*64 + sk);
    #pragma unroll
    for (int p = 0; p < 4; ++p)
      gl16(gb + p*32768, Bs + p*4096 + arow*64 + sk);
  };

  STAGE(0, 0);
  STAGE(1, 1);
  int cur = 0;
  for (int t = 0; t < 8; ++t) {
    if (t + 2 < 8) {
      STAGE((cur + 2) % 3, t + 2);
      asm volatile("s_waitcnt vmcnt(12)" ::: "memory");
    } else if (t + 1 < 8) {
      asm volatile("s_waitcnt vmcnt(6)" ::: "memory");
    } else {
      asm volatile("s_waitcnt vmcnt(0)" ::: "memory");
    }
    __builtin_amdgcn_sched_barrier(0);
    __builtin_amdgcn_s_barrier();
    const char* As = lds + cur * 24576;
    const char* Bs = As + 8192;
    bf16x8 af[4], bf8[8];
    #pragma unroll
    for (int i = 0; i < 4; ++i)
      af[i] = *(const bf16x8*)(As + (wm + i*16 + lo)*64 + hi*16);
    #pragma unroll
    for (int j = 0; j < 8; ++j)
      bf8[j] = *(const bf16x8*)(Bs + (wn + j*16 + lo)*64 + hi*16);
    #pragma unroll
    for (int i = 0; i < 4; ++i)
      #pragma unroll
      for (int j = 0; j < 8; ++j)
        acc[i][j] = mfma16(af[i], bf8[j], acc[i][j]);
    __builtin_amdgcn_s_barrier();
    cur = (cur + 1) % 3;
  }

  __syncthreads();
  float* LsE = (float*)lds;            // [2][32][260] f32
  const int c4 = (tid & 3) * 4;
  const int row64 = tid >> 2;
  const int reg = row64 >> 5, rloc = row64 & 31;
  #pragma unroll
  for (int rr = 0; rr < 2; ++rr) {
    #pragma unroll
    for (int i2 = 0; i2 < 2; ++i2) {
      const int i = rr*2 + i2;
      #pragma unroll
      for (int j = 0; j < 8; ++j)
        #pragma unroll
        for (int r = 0; r < 4; ++r)
          LsE[wmh*8320 + (i2*16 + hi*4 + r)*260 + wn + j*16 + lo] = acc[i][j][r];
    }
    __syncthreads();
    const int grow = bm + reg*64 + rr*32 + rloc;
    f32x4 d2[16];
    float sum = 0.f, sq = 0.f;
    #pragma unroll
    for (int k = 0; k < 16; ++k) {
      const int col = c4 + k*16;
      f32x4 v = *(const f32x4*)&LsE[reg*8320 + rloc*260 + col];
      v += *(const f32x4*)(bias + col);
      v += *(const f32x4*)(resid + (size_t)grow*256 + col);
      d2[k] = v;
      sum += v[0] + v[1] + v[2] + v[3];
      sq  += v[0]*v[0] + v[1]*v[1] + v[2]*v[2] + v[3]*v[3];
      *(f32x4*)(out + (size_t)grow*256 + col) = v;
    }
    sum += __shfl_xor(sum, 1); sq += __shfl_xor(sq, 1);
    sum += __shfl_xor(sum, 2); sq += __shfl_xor(sq, 2);
    const float mean = sum * (1.f/256.f);
    const float rs = rsqrtf(sq * (1.f/256.f) - mean*mean + 1e-5f);
    #pragma unroll
    for (int k = 0; k < 16; ++k) {
      const int col = c4 + k*16;
      const f32x4 gv = *(const f32x4*)(g2 + col);
      const f32x4 bvv = *(const f32x4*)(b2 + col);
      u16x4 o;
      #pragma unroll
      for (int d = 0; d < 4; ++d)
        o[d] = f2bf((d2[k][d] - mean) * rs * gv[d] + bvv[d]);
      *(u16x4*)(xln + (size_t)grow*256 + col) = o;
    }
    __syncthreads();
  }
}

// ---- fused window attention: one block per window, 2 heads per wave ----
__global__ __launch_bounds__(256, 2)
void attn_kernel(const bf16u* __restrict__ qkv, const float* __restrict__ mask,
                 const int* __restrict__ relp, const float* __restrict__ rpe,
                 bf16u* __restrict__ outp) {
  const int w = blockIdx.x;
  const int tid = threadIdx.x, lane = tid & 63, wv = tid >> 6;
  const int lo = lane & 15, hi = lane >> 4;

  __shared__ __align__(16) bf16u sQK[32*520];
  __shared__ __align__(16) bf16u sV[32][264];
  __shared__ __align__(16) bf16u sP[4][32][44];
  __shared__ float sTabT[8][156];
  __shared__ int sRel[1024];
  __shared__ float sMask[32][33];

  const size_t qbase = (size_t)w * (32*768);
  {
    #pragma unroll
    for (int t = 0; t < 8; ++t) {
      int i = tid + t*256;
      int tok = i >> 6;
      int cb = (i & 63) * 16;
      *(u16x8*)((char*)sQK + tok*1040 + cb) =
          *(const u16x8*)((const char*)(qkv + qbase) + tok*1536 + cb);
    }
    #pragma unroll
    for (int t = 0; t < 4; ++t) {
      int i = tid + t*256;
      int tok = i >> 5, c8 = i & 31;
      *(u16x8*)&sV[tok][c8*8] = *(const u16x8*)(qkv + qbase + tok*768 + 512 + c8*8);
    }
    for (int i = tid; i < 1224; i += 256)
      sTabT[i & 7][i >> 3] = rpe[i];
    #pragma unroll
    for (int t = 0; t < 4; ++t) {
      int i = tid + t*256;
      const int* rp = relp + ((size_t)w*1024 + i)*3;
      int r0 = rp[0], r1 = rp[1], r2 = rp[2];
      r0 = min(max(r0, -25), 25) + 25;
      r1 = min(max(r1, -25), 25) + 76;
      r2 = min(max(r2, -25), 25) + 127;
      sRel[i] = r0 | (r1 << 8) | (r2 << 16);
    }
    #pragma unroll
    for (int d = 0; d < 4; ++d) {
      int i = tid*4 + d;
      sMask[i >> 5][i & 31] = mask[(size_t)w*1024 + i];
    }
  }
  __syncthreads();

  const float scale = 0.17677669529663687f;
  #pragma unroll
  for (int e = 0; e < 2; ++e) {
    const int h = wv*2 + e;
    bf16x8 qf[2], kf[2];
    #pragma unroll
    for (int rf = 0; rf < 2; ++rf) {
      int tok = rf*16 + lo;
      qf[rf] = *(const bf16x8*)((const char*)sQK + tok*1040 + h*64 + hi*16);
      kf[rf] = *(const bf16x8*)((const char*)sQK + tok*1040 + 512 + h*64 + hi*16);
    }
    f32x4 S[2][2] = {};
    #pragma unroll
    for (int rf = 0; rf < 2; ++rf)
      #pragma unroll
      for (int cf = 0; cf < 2; ++cf)
        S[rf][cf] = mfma16(qf[rf], kf[cf], S[rf][cf]);
    #pragma unroll
    for (int rf = 0; rf < 2; ++rf)
      #pragma unroll
      for (int cf = 0; cf < 2; ++cf)
        #pragma unroll
        for (int r = 0; r < 4; ++r) {
          const int qq = rf*16 + hi*4 + r;
          const int kk = cf*16 + lo;
          const int pk = sRel[qq*32 + kk];
          const float bsum = sTabT[h][pk & 255] + sTabT[h][(pk >> 8) & 255]
                           + sTabT[h][(pk >> 16) & 255];
          S[rf][cf][r] = S[rf][cf][r] * scale + bsum + sMask[qq][kk];
        }
    #pragma unroll
    for (int rf = 0; rf < 2; ++rf)
      #pragma unroll
      for (int r = 0; r < 4; ++r) {
        float m0 = fmaxf(S[rf][0][r], S[rf][1][r]);
        #pragma unroll
        for (int d = 1; d < 16; d <<= 1) m0 = fmaxf(m0, __shfl_xor(m0, d));
        const float p0 = __expf(S[rf][0][r] - m0);
        const float p1 = __expf(S[rf][1][r] - m0);
        float ss = p0 + p1;
        #pragma unroll
        for (int d = 1; d < 16; d <<= 1) ss += __shfl_xor(ss, d);
        const float inv = 1.f / ss;
        S[rf][0][r] = p0 * inv;
        S[rf][1][r] = p1 * inv;
      }
    #pragma unroll
    for (int rf = 0; rf < 2; ++rf)
      #pragma unroll
      for (int cf = 0; cf < 2; ++cf)
        #pragma unroll
        for (int r = 0; r < 4; ++r)
          sP[wv][rf*16 + hi*4 + r][cf*16 + lo] = f2bf(S[rf][cf][r]);
    f32x4 O[2][2] = {};
    #pragma unroll
    for (int rf = 0; rf < 2; ++rf) {
      bf16x8 pf;
      *(u16x4*)&pf       = *(const u16x4*)&sP[wv][rf*16 + lo][hi*8];
      *((u16x4*)&pf + 1) = *(const u16x4*)&sP[wv][rf*16 + lo][hi*8 + 4];
      #pragma unroll
      for (int cf = 0; cf < 2; ++cf) {
        bf16x8 vf;
        #pragma unroll
        for (int j = 0; j < 8; ++j)
          ((bf16u*)&vf)[j] = sV[hi*8 + j][h*32 + cf*16 + lo];
        O[rf][cf] = mfma16(pf, vf, O[rf][cf]);
      }
    }
    #pragma unroll
    for (int rf = 0; rf < 2; ++rf)
      #pragma unroll
      for (int cf = 0; cf < 2; ++cf)
        #pragma unroll
        for (int r = 0; r < 4; ++r) {
          const int qq = rf*16 + hi*4 + r;
          outp[(size_t)(w*32 + qq)*256 + h*32 + cf*16 + lo] = f2bf(O[rf][cf][r]);
        }
  }
}

extern "C" void kernel_launch(void* const* d_in, const int* in_sizes, int n_in,
                              void* d_out, int out_size, void* d_ws, size_t ws_size,
                              hipStream_t stream) {
  const float* data   = (const float*)d_in[0];
  const float* mask   = (const float*)d_in[1];
  const int*   relp   = (const int*)d_in[2];
  const float* qkv_w  = (const float*)d_in[3];
  const float* qkv_b  = (const float*)d_in[4];
  const float* proj_w = (const float*)d_in[5];
  const float* proj_b = (const float*)d_in[6];
  const float* rpe    = (const float*)d_in[7];
  const float* ln1_g  = (const float*)d_in[8];
  const float* ln1_b  = (const float*)d_in[9];
  const float* ln2_g  = (const float*)d_in[10];
  const float* ln2_b  = (const float*)d_in[11];
  const float* fc1_w  = (const float*)d_in[12];
  const float* fc1_b  = (const float*)d_in[13];
  const float* fc2_w  = (const float*)d_in[14];
  const float* fc2_b  = (const float*)d_in[15];

  char* ws = (char*)d_ws;
  bf16u* wt_qkv  = (bf16u*)(ws);                 // 768x256
  bf16u* wt_proj = (bf16u*)(ws + 393216);        // 256x256
  bf16u* wt_fc1  = (bf16u*)(ws + 524288);        // 1024x256
  bf16u* wt_fc2  = (bf16u*)(ws + 1048576);       // 256x1024
  char*  big     = ws + 2097152;
  bf16u* xbuf    = (bf16u*)big;                        // attn out (67MB)
  bf16u* qkvbuf  = (bf16u*)(big + 67108864);           // qkv (201MB)
  bf16u* h1      = (bf16u*)big;                        // fc1 out (overlays dead bufs)
  bf16u* xnorm   = (bf16u*)(big + 268435456);          // ln1-out / fused-ln2-out
  float* data2   = (float*)d_out;                // residual stream lives in d_out

  wprep_kernel<<<768, 256, 0, stream>>>(qkv_w, wt_qkv, 256, 768);
  wprep_kernel<<<256, 256, 0, stream>>>(proj_w, wt_proj, 256, 256);
  wprep_kernel<<<1024, 256, 0, stream>>>(fc1_w, wt_fc1, 256, 1024);
  wprep_kernel<<<1024, 256, 0, stream>>>(fc2_w, wt_fc2, 1024, 256);

  ln_kernel<<<32768, 256, 0, stream>>>(data, ln1_g, ln1_b, xnorm);
  gemm256_kernel<0><<<512*3, 512, 0, stream>>>(xnorm, wt_qkv, qkv_b, nullptr,
                                               qkvbuf, 768, 256, 3);
  attn_kernel<<<NWIN, 256, 0, stream>>>(qkvbuf, mask, relp, rpe, xbuf);
  gemmP_kernel<<<1024, 256, 0, stream>>>(xbuf, wt_proj, proj_b, data,
                                         data2, xnorm, ln2_g, ln2_b);
  gemm256_kernel<1><<<512*4, 512, 0, stream>>>(xnorm, wt_fc1, fc1_b, nullptr,
                                               h1, 1024, 256, 4);
  gemm256_kernel<2><<<512*1, 512, 0, stream>>>(h1, wt_fc2, fc2_b, data2,
                                               d_out, 256, 1024, 1);
}